// Round 1
// baseline (319.920 us; speedup 1.0000x reference)
//
#include <hip/hip_runtime.h>

typedef __bf16 bf16_t;
typedef __bf16 bf16x8 __attribute__((ext_vector_type(8)));
typedef float f32x4 __attribute__((ext_vector_type(4)));
typedef unsigned short us4 __attribute__((ext_vector_type(4)));
typedef unsigned short us8 __attribute__((ext_vector_type(8)));

// ---------------- foveation ----------------
// glimpse[b, (k*3+c)*1024 + gy*32 + gx] = avgpool_F( x[b,c, st1-pad+gy*F+dy, st0-pad+gx*F+dx] )
template<int F>
__device__ __forceinline__ void fov_scale(const float* __restrict__ xb,
                                          bf16_t* __restrict__ gb,
                                          int r0, int c0, int base, int count, int kidx)
{
  constexpr float inv = 1.0f / (F * F);
  for (int i = threadIdx.x; i < count; i += 256) {
    const int idx = base + i;              // 0..3071 within this scale (c*1024 + gy*32 + gx)
    const int ch  = idx >> 10;
    const int rem = idx & 1023;
    const int gy  = rem >> 5, gx = rem & 31;
    const float* xc = xb + ch * 50176;
    float sum = 0.0f;
    const int rbase = r0 + gy * F, cbase = c0 + gx * F;
#pragma unroll
    for (int dy = 0; dy < F; ++dy) {
      const int rr = rbase + dy;
      if ((unsigned)rr < 224u) {
#pragma unroll
        for (int dx = 0; dx < F; ++dx) {
          const int cc = cbase + dx;
          if ((unsigned)cc < 224u) sum += xc[rr * 224 + cc];
        }
      }
    }
    gb[kidx * 3072 + idx] = (bf16_t)(sum * inv);
  }
}

__global__ __launch_bounds__(256) void foveate_kernel(const float* __restrict__ x,
                                                      const float* __restrict__ l,
                                                      bf16_t* __restrict__ g)
{
  const int b = blockIdx.x;
  const float l0 = l[2 * b], l1 = l[2 * b + 1];
  // match reference exactly: (int)(0.5f * ((l + 1.0f) * 224.0f)), trunc (values >= 0)
  const int st0 = (int)(0.5f * ((l0 + 1.0f) * 224.0f));  // col start
  const int st1 = (int)(0.5f * ((l1 + 1.0f) * 224.0f));  // row start
  const float* xb = x + (size_t)b * 3 * 50176;
  bf16_t* gb = g + (size_t)b * 9216;
  const int y = blockIdx.y;  // 7 work partitions weighted by read cost
  if (y == 0) {
    fov_scale<1>(xb, gb, st1 - 17, st0 - 17, 0, 3072, 0);            // pad = 32/2+1
  } else if (y <= 2) {
    fov_scale<2>(xb, gb, st1 - 33, st0 - 33, (y - 1) * 1536, 1536, 1); // pad = 64/2+1
  } else {
    fov_scale<4>(xb, gb, st1 - 65, st0 - 65, (y - 3) * 768, 768, 2);   // pad = 128/2+1
  }
}

// ---------------- split-K bf16 MFMA GEMM ----------------
// A: bf16 [M x KFULL] row-major (k contiguous). B: fp32 [KFULL x NDIM] row-major,
// rows k < KB1 from Bp0, else Bp1 (lets GEMM2 use concatenated [W3;W4]).
// Writes fp32 partials: part[z][m][n], z = blockIdx.z (split index).
template<int BM, int BN, int KCHUNK, int NDIM, int KFULL, int KB1>
__global__ __launch_bounds__(256) void gemm_split(const bf16_t* __restrict__ A,
                                                  const float* __restrict__ Bp0,
                                                  const float* __restrict__ Bp1,
                                                  float* __restrict__ part, int Mdim)
{
  constexpr int WROWS = BM / 4;     // rows per wave
  constexpr int SM = WROWS / 16;    // 16-row subtiles per wave
  constexpr int SN = BN / 16;       // 16-col subtiles
  constexpr int LDA = 36;           // LDS row stride (ushorts): odd*2 banks -> conflict-free b64
  __shared__ unsigned short Al[BM * LDA];
  __shared__ unsigned short Bl[BN * LDA];
  const int t = threadIdx.x;
  const int w = t >> 6, lane = t & 63;
  const int lr = lane & 15, kg = lane >> 4;
  const int bm0 = blockIdx.x * BM, bn0 = blockIdx.y * BN;
  const int ks0 = blockIdx.z * KCHUNK;

  f32x4 acc[SM][SN] = {};

  for (int k0 = 0; k0 < KCHUNK; k0 += 32) {
    const int kbase = ks0 + k0;
    // ---- stage A tile (already bf16, k-contiguous): 16B global, 2x8B LDS writes ----
#pragma unroll
    for (int i = 0; i < BM / 64; ++i) {
      const int q = t + 256 * i;
      const int m = q >> 2, kb = (q & 3) * 8;
      us8 v = *(const us8*)(A + (size_t)(bm0 + m) * KFULL + kbase + kb);
      *(us4*)(&Al[m * LDA + kb])     = __builtin_shufflevector(v, v, 0, 1, 2, 3);
      *(us4*)(&Al[m * LDA + kb + 4]) = __builtin_shufflevector(v, v, 4, 5, 6, 7);
    }
    // ---- stage B tile: fp32 coalesced read, convert bf16, transpose to [n][k] ----
    {
      const int k = t >> 3, nb = (t & 7) * 8;
      const int gk = kbase + k;
      const float* brow = (gk < KB1) ? (Bp0 + (size_t)gk * NDIM)
                                     : (Bp1 + (size_t)(gk - KB1) * NDIM);
      const float4 f0 = *(const float4*)(brow + bn0 + nb);
      const float4 f1 = *(const float4*)(brow + bn0 + nb + 4);
      const float fs[8] = {f0.x, f0.y, f0.z, f0.w, f1.x, f1.y, f1.z, f1.w};
#pragma unroll
      for (int j = 0; j < 8; ++j)
        Bl[(nb + j) * LDA + k] = __builtin_bit_cast(unsigned short, (bf16_t)fs[j]);
    }
    __syncthreads();
    // ---- fragments (A[m=lr][k=kg*8+j], B[n=lr][k=kg*8+j]) + MFMA ----
    bf16x8 af[SM], bfr[SN];
#pragma unroll
    for (int sm = 0; sm < SM; ++sm) {
      const unsigned short* p = &Al[(w * WROWS + sm * 16 + lr) * LDA + kg * 8];
      us4 x0 = *(const us4*)p;
      us4 x1 = *(const us4*)(p + 4);
      af[sm] = __builtin_bit_cast(bf16x8, __builtin_shufflevector(x0, x1, 0, 1, 2, 3, 4, 5, 6, 7));
    }
#pragma unroll
    for (int sn = 0; sn < SN; ++sn) {
      const unsigned short* p = &Bl[(sn * 16 + lr) * LDA + kg * 8];
      us4 x0 = *(const us4*)p;
      us4 x1 = *(const us4*)(p + 4);
      bfr[sn] = __builtin_bit_cast(bf16x8, __builtin_shufflevector(x0, x1, 0, 1, 2, 3, 4, 5, 6, 7));
    }
#pragma unroll
    for (int sm = 0; sm < SM; ++sm)
#pragma unroll
      for (int sn = 0; sn < SN; ++sn)
        acc[sm][sn] = __builtin_amdgcn_mfma_f32_16x16x32_bf16(af[sm], bfr[sn], acc[sm][sn], 0, 0, 0);
    __syncthreads();
  }
  // ---- write fp32 partials (C/D layout: col=lr, row=kg*4+r) ----
  float* outp = part + (size_t)blockIdx.z * ((size_t)Mdim * NDIM);
#pragma unroll
  for (int sm = 0; sm < SM; ++sm)
#pragma unroll
    for (int sn = 0; sn < SN; ++sn)
#pragma unroll
      for (int r = 0; r < 4; ++r) {
        const int gm = bm0 + w * WROWS + sm * 16 + kg * 4 + r;
        const int gn = bn0 + sn * 16 + lr;
        outp[(size_t)gm * NDIM + gn] = acc[sm][sn][r];
      }
}

// ---------------- reduce GEMM1 partials + bias + relu -> bf16; also l_out path ----------------
// A2 = [ relu(glimpse@W1+b1) | relu(l_prev@W2+b2) ]  (256 x 2048, bf16)
__global__ __launch_bounds__(256) void fuse_mid(const float* __restrict__ part1,
                                                const float* __restrict__ b1,
                                                const float* __restrict__ lprev,
                                                const float* __restrict__ W2,
                                                const float* __restrict__ b2,
                                                bf16_t* __restrict__ A2)
{
  const int idx = blockIdx.x * 256 + threadIdx.x;  // 0..524287; block-uniform branch (col chunk of 256)
  const int row = idx >> 11, col = idx & 2047;
  float s;
  if (col < 1024) {
    s = b1[col];
#pragma unroll
    for (int i = 0; i < 8; ++i) s += part1[i * 262144 + row * 1024 + col];
  } else {
    const int n = col - 1024;
    s = fmaf(lprev[2 * row], W2[n], fmaf(lprev[2 * row + 1], W2[1024 + n], b2[n]));
  }
  A2[idx] = (bf16_t)fmaxf(s, 0.0f);
}

// ---------------- reduce GEMM2 partials + (b3+b4) + relu -> fp32 out ----------------
__global__ __launch_bounds__(256) void epilogue2(const float* __restrict__ part2,
                                                 const float* __restrict__ b3,
                                                 const float* __restrict__ b4,
                                                 float* __restrict__ out)
{
  const int idx = blockIdx.x * 256 + threadIdx.x;  // 0..524287
  const int col = idx & 2047;
  float s = b3[col] + b4[col];
#pragma unroll
  for (int i = 0; i < 4; ++i) s += part2[i * 524288 + idx];
  out[idx] = fmaxf(s, 0.0f);
}

extern "C" void kernel_launch(void* const* d_in, const int* in_sizes, int n_in,
                              void* d_out, int out_size, void* d_ws, size_t ws_size,
                              hipStream_t stream)
{
  const float* x     = (const float*)d_in[0];
  const float* lprev = (const float*)d_in[1];
  const float* W1    = (const float*)d_in[2];   // (9216, 1024)
  const float* b1    = (const float*)d_in[3];
  const float* W2    = (const float*)d_in[4];   // (2, 1024)
  const float* b2    = (const float*)d_in[5];
  const float* W3    = (const float*)d_in[6];   // (1024, 2048)
  const float* b3    = (const float*)d_in[7];
  const float* W4    = (const float*)d_in[8];   // (1024, 2048)
  const float* b4    = (const float*)d_in[9];
  float* out = (float*)d_out;

  // workspace layout (all 16B aligned), total ~21.5 MB
  char* ws = (char*)d_ws;
  bf16_t* glimpse = (bf16_t*)ws;                 // 256*9216*2   = 4,718,592 B
  bf16_t* A2      = (bf16_t*)(ws + 4718592);     // 256*2048*2   = 1,048,576 B
  float*  part1   = (float*)(ws + 5767168);      // 8*256*1024*4 = 8,388,608 B
  float*  part2   = (float*)(ws + 14155776);     // 4*256*2048*4 = 8,388,608 B

  foveate_kernel<<<dim3(256, 7), 256, 0, stream>>>(x, lprev, glimpse);
  // GEMM1: M=256,N=1024,K=9216; 128x64 tiles, splitK=8 (chunk 1152) -> 2*16*8 = 256 blocks
  gemm_split<128, 64, 1152, 1024, 9216, 9216>
      <<<dim3(2, 16, 8), 256, 0, stream>>>(glimpse, W1, W1, part1, 256);
  fuse_mid<<<2048, 256, 0, stream>>>(part1, b1, lprev, W2, b2, A2);
  // GEMM2: M=256,N=2048,K=2048 ([g_out|l_out]@[W3;W4]); 64x64 tiles, splitK=4 -> 4*32*4 = 512 blocks
  gemm_split<64, 64, 512, 2048, 2048, 1024>
      <<<dim3(4, 32, 4), 256, 0, stream>>>(A2, W3, W4, part2, 256);
  epilogue2<<<2048, 256, 0, stream>>>(part2, b3, b4, out);
}